// Round 1
// baseline (832.536 us; speedup 1.0000x reference)
//
#include <hip/hip_runtime.h>

// GCN pipeline on MI355X:
//   deg/dinv -> CSR(by dst) -> GEMM1(f16 MFMA) -> agg+relu -> GEMM2 -> agg+relu
//   -> BN stats -> fused BN+LN -> out
// All fp32 except GEMM inputs (cvt to f16; fp32 MFMA accumulate).

typedef __attribute__((ext_vector_type(4))) float f32x4;
typedef __attribute__((ext_vector_type(8))) _Float16 f16x8;
typedef __attribute__((ext_vector_type(4))) _Float16 f16x4;

#define NN 50000
#define NF 1024
#define NH 256

// ---------------- small kernels: degree / dinv -------------------------------
__global__ __launch_bounds__(256) void deg_count(const int* __restrict__ ei,
    const float* __restrict__ ew, float* __restrict__ deg, int* __restrict__ cnt, int E)
{
    int e = blockIdx.x * 256 + threadIdx.x;
    if (e >= E) return;
    int d = ei[E + e];              // edge_index[1][e]
    atomicAdd(&deg[d], ew[e]);
    atomicAdd(&cnt[d], 1);
}

__global__ __launch_bounds__(256) void dinv_k(const float* __restrict__ deg,
    float* __restrict__ dinv, int n)
{
    int i = blockIdx.x * 256 + threadIdx.x;
    if (i < n) dinv[i] = rsqrtf(deg[i] + 1.0f);   // +1 = self-loop weight
}

// ---------------- CSR build: 3-kernel exclusive scan + scatter ---------------
__global__ __launch_bounds__(512) void scan_a(const int* __restrict__ cnt,
    int* __restrict__ excl, int* __restrict__ bsum, int n)
{
    __shared__ int sm[512];
    int t = threadIdx.x, g = blockIdx.x * 512 + t;
    int v = (g < n) ? cnt[g] : 0;
    sm[t] = v;
    __syncthreads();
    for (int d = 1; d < 512; d <<= 1) {
        int x = (t >= d) ? sm[t - d] : 0;
        __syncthreads();
        sm[t] += x;
        __syncthreads();
    }
    if (g < n) excl[g] = sm[t] - v;
    if (t == 511) bsum[blockIdx.x] = sm[511];
}

__global__ __launch_bounds__(128) void scan_b(int* __restrict__ bsum, int nb)
{
    __shared__ int sm[128];
    int t = threadIdx.x;
    int v = (t < nb) ? bsum[t] : 0;
    sm[t] = v;
    __syncthreads();
    for (int d = 1; d < 128; d <<= 1) {
        int x = (t >= d) ? sm[t - d] : 0;
        __syncthreads();
        sm[t] += x;
        __syncthreads();
    }
    if (t < nb) bsum[t] = sm[t] - v;   // exclusive block base
}

__global__ __launch_bounds__(256) void scan_c(const int* __restrict__ excl,
    const int* __restrict__ bsum, int* __restrict__ offs, int n, int E)
{
    int g = blockIdx.x * 256 + threadIdx.x;
    if (g < n) offs[g] = excl[g] + bsum[g >> 9];
    else if (g == n) offs[n] = E;
}

__global__ __launch_bounds__(256) void scatter_k(const int* __restrict__ ei,
    const float* __restrict__ ew, const int* __restrict__ offs,
    int* __restrict__ cursor, const float* __restrict__ dinv,
    int* __restrict__ csrc, float* __restrict__ cwv, int E)
{
    int e = blockIdx.x * 256 + threadIdx.x;
    if (e >= E) return;
    int s = ei[e], d = ei[E + e];
    int pos = offs[d] + atomicAdd(&cursor[d], 1);
    csrc[pos] = s;
    cwv[pos] = ew[e] * dinv[s] * dinv[d];   // symmetric norm
}

// ---------------- W -> W^T f16 conversion ------------------------------------
// W is [K][256] row-major fp32; WT is [256][K] f16.
__global__ __launch_bounds__(256) void cvt_w(const float* __restrict__ W,
    unsigned short* __restrict__ WT, int K, int total)
{
    int idx = blockIdx.x * 256 + threadIdx.x;
    if (idx >= total) return;
    int k = idx >> 8, n = idx & 255;
    ((_Float16*)WT)[(size_t)n * K + k] = (_Float16)W[idx];
}

// ---------------- GEMM: C[M][256] = A[M][K](fp32) * B[K][256], f16 MFMA ------
// 128x128 tile, 256 threads = 4 waves (2x2), each wave 64x64 via 4x4 16x16x32.
// A staged fp32->f16 via ds_write_b64; B^T staged via global_load_lds (16B).
__global__ __launch_bounds__(256) void gemm_f16(
    const float* __restrict__ A, const unsigned short* __restrict__ BT,
    float* __restrict__ C, int M, int K)
{
    __shared__ _Float16 As[128 * 32];   // [m][k]
    __shared__ _Float16 Bs[128 * 32];   // [n][k]
    const int t = threadIdx.x;
    const int lane = t & 63, wid = t >> 6;
    const int r = lane & 15, q = lane >> 4;
    const int n0 = blockIdx.x * 128;          // x = N-tile so A-tile reuse is adjacent
    const int m0 = blockIdx.y * 128;
    const int wm = (wid >> 1) * 64, wn = (wid & 1) * 64;

    f32x4 acc[4][4];
#pragma unroll
    for (int i = 0; i < 4; ++i) {
#pragma unroll
        for (int j = 0; j < 4; ++j) acc[i][j] = (f32x4){0.f, 0.f, 0.f, 0.f};
    }

    for (int k0 = 0; k0 < K; k0 += 32) {
        // stage A: 128x32 floats, 4 float4 per thread, cvt to f16
#pragma unroll
        for (int it = 0; it < 4; ++it) {
            int f = it * 256 + t;
            int m = f >> 3, kc = (f & 7) << 2;
            int gm = m0 + m; if (gm >= M) gm = M - 1;   // clamp; garbage rows masked at store
            const float4 v = *(const float4*)(A + (size_t)gm * K + (k0 + kc));
            f16x4 hv;
            hv.x = (_Float16)v.x; hv.y = (_Float16)v.y;
            hv.z = (_Float16)v.z; hv.w = (_Float16)v.w;
            *(f16x4*)(As + m * 32 + kc) = hv;
        }
        // stage B^T via async global->LDS, 16B/lane, 2 rounds (8KB total)
#pragma unroll
        for (int rd = 0; rd < 2; ++rd) {
            int c = rd * 256 + t;
            int n = c >> 2, kc = (c & 3) << 3;
            const unsigned short* g = BT + (size_t)(n0 + n) * K + (k0 + kc);
            _Float16* l = Bs + (size_t)(rd * 256 + wid * 64) * 8;  // wave-uniform base
            __builtin_amdgcn_global_load_lds(
                (const __attribute__((address_space(1))) unsigned int*)g,
                (__attribute__((address_space(3))) unsigned int*)l, 16, 0, 0);
        }
        __syncthreads();
        f16x8 af[4], bfr[4];
#pragma unroll
        for (int i = 0; i < 4; ++i)
            af[i] = *(const f16x8*)(As + (wm + i * 16 + r) * 32 + q * 8);
#pragma unroll
        for (int j = 0; j < 4; ++j)
            bfr[j] = *(const f16x8*)(Bs + (wn + j * 16 + r) * 32 + q * 8);
#pragma unroll
        for (int i = 0; i < 4; ++i) {
#pragma unroll
            for (int j = 0; j < 4; ++j)
                acc[i][j] = __builtin_amdgcn_mfma_f32_16x16x32_f16(af[i], bfr[j], acc[i][j], 0, 0, 0);
        }
        __syncthreads();
    }
    // epilogue: D[row=q*4+reg][col=r] per 16x16 tile (verified C/D mapping)
#pragma unroll
    for (int i = 0; i < 4; ++i) {
#pragma unroll
        for (int reg = 0; reg < 4; ++reg) {
            int m = m0 + wm + i * 16 + q * 4 + reg;
            if (m < M) {
                float* cp = C + (size_t)m * 256 + (n0 + wn + r);
#pragma unroll
                for (int j = 0; j < 4; ++j) cp[j * 16] = acc[i][j][reg];
            }
        }
    }
}

// ---------------- aggregation: out[i] = relu(sum_e norm*h[src] + dinv_i^2*h[i] + b)
// 1 wave per node, lane holds cols [4*lane, 4*lane+4)
__global__ __launch_bounds__(256) void agg_relu(
    const float* __restrict__ h, const int* __restrict__ roff,
    const int* __restrict__ csrc, const float* __restrict__ cwv,
    const float* __restrict__ dinv, const float* __restrict__ bias,
    float* __restrict__ out, int n)
{
    const int lane = threadIdx.x & 63, wid = threadIdx.x >> 6;
    const int i = blockIdx.x * 4 + wid;
    if (i >= n) return;
    const int c = lane << 2;
    const float di = dinv[i];
    const float sw = di * di;
    const float4 hv = *(const float4*)(h + (size_t)i * 256 + c);
    float a0 = sw * hv.x, a1 = sw * hv.y, a2 = sw * hv.z, a3 = sw * hv.w;
    float c0 = 0.f, c1 = 0.f, c2 = 0.f, c3 = 0.f;
    int p = roff[i];
    const int pe = roff[i + 1];
    for (; p + 1 < pe; p += 2) {        // unroll x2: two independent load chains
        int s0 = csrc[p], s1 = csrc[p + 1];
        float w0 = cwv[p], w1 = cwv[p + 1];
        float4 v0 = *(const float4*)(h + (size_t)s0 * 256 + c);
        float4 v1 = *(const float4*)(h + (size_t)s1 * 256 + c);
        a0 += w0 * v0.x; a1 += w0 * v0.y; a2 += w0 * v0.z; a3 += w0 * v0.w;
        c0 += w1 * v1.x; c1 += w1 * v1.y; c2 += w1 * v1.z; c3 += w1 * v1.w;
    }
    if (p < pe) {
        int s0 = csrc[p]; float w0 = cwv[p];
        float4 v0 = *(const float4*)(h + (size_t)s0 * 256 + c);
        a0 += w0 * v0.x; a1 += w0 * v0.y; a2 += w0 * v0.z; a3 += w0 * v0.w;
    }
    const float4 bb = *(const float4*)(bias + c);
    float4 o;
    o.x = fmaxf(a0 + c0 + bb.x, 0.f);
    o.y = fmaxf(a1 + c1 + bb.y, 0.f);
    o.z = fmaxf(a2 + c2 + bb.z, 0.f);
    o.w = fmaxf(a3 + c3 + bb.w, 0.f);
    *(float4*)(out + (size_t)i * 256 + c) = o;
}

// ---------------- BatchNorm stats (per-column over 50000 rows) ---------------
__global__ __launch_bounds__(256) void bn_stats(const float* __restrict__ h,
    float* __restrict__ bnsum, float* __restrict__ bnsq, int n)
{
    const int t = threadIdx.x;             // column
    float s = 0.f, s2 = 0.f;
    for (int r = blockIdx.x; r < n; r += gridDim.x) {
        float v = h[(size_t)r * 256 + t];
        s += v; s2 += v * v;
    }
    atomicAdd(&bnsum[t], s);
    atomicAdd(&bnsq[t], s2);
}

__global__ __launch_bounds__(256) void bn_params(const float* __restrict__ bnsum,
    const float* __restrict__ bnsq, const float* __restrict__ gamma,
    const float* __restrict__ beta, float* __restrict__ scale,
    float* __restrict__ shift, int n)
{
    int t = threadIdx.x;
    float mu = bnsum[t] / (float)n;
    float var = bnsq[t] / (float)n - mu * mu;     // biased variance
    float sc = gamma[t] * rsqrtf(var + 1e-5f);
    scale[t] = sc;
    shift[t] = beta[t] - mu * sc;
}

// ---------------- fused BN affine + LayerNorm --------------------------------
__global__ __launch_bounds__(256) void bn_ln(const float* __restrict__ h,
    const float* __restrict__ scale, const float* __restrict__ shift,
    const float* __restrict__ lng, const float* __restrict__ lnb,
    float* __restrict__ out, int n)
{
    const int lane = threadIdx.x & 63, wid = threadIdx.x >> 6;
    const int i = blockIdx.x * 4 + wid;
    if (i >= n) return;
    const int c = lane << 2;
    const float4 v = *(const float4*)(h + (size_t)i * 256 + c);
    const float4 sc = *(const float4*)(scale + c);
    const float4 sh = *(const float4*)(shift + c);
    float y0 = v.x * sc.x + sh.x;
    float y1 = v.y * sc.y + sh.y;
    float y2 = v.z * sc.z + sh.z;
    float y3 = v.w * sc.w + sh.w;
    float ps = y0 + y1 + y2 + y3;
    float ps2 = y0 * y0 + y1 * y1 + y2 * y2 + y3 * y3;
#pragma unroll
    for (int off = 32; off > 0; off >>= 1) {
        ps += __shfl_down(ps, off);
        ps2 += __shfl_down(ps2, off);
    }
    ps = __shfl(ps, 0);
    ps2 = __shfl(ps2, 0);
    const float mu = ps * (1.f / 256.f);
    const float var = ps2 * (1.f / 256.f) - mu * mu;
    const float rs = rsqrtf(var + 1e-5f);
    const float4 g = *(const float4*)(lng + c);
    const float4 bb = *(const float4*)(lnb + c);
    float4 o;
    o.x = (y0 - mu) * rs * g.x + bb.x;
    o.y = (y1 - mu) * rs * g.y + bb.y;
    o.z = (y2 - mu) * rs * g.z + bb.z;
    o.w = (y3 - mu) * rs * g.w + bb.w;
    *(float4*)(out + (size_t)i * 256 + c) = o;
}

// ---------------- launcher ---------------------------------------------------
extern "C" void kernel_launch(void* const* d_in, const int* in_sizes, int n_in,
                              void* d_out, int out_size, void* d_ws, size_t ws_size,
                              hipStream_t stream)
{
    const float* x   = (const float*)d_in[0];
    const int*   ei  = (const int*)d_in[1];     // [2][E] int32
    const float* ew  = (const float*)d_in[2];
    const float* W1  = (const float*)d_in[3];
    const float* b1  = (const float*)d_in[4];
    const float* W2  = (const float*)d_in[5];
    const float* b2  = (const float*)d_in[6];
    const float* bng = (const float*)d_in[7];
    const float* bnb = (const float*)d_in[8];
    const float* lng = (const float*)d_in[9];
    const float* lnb = (const float*)d_in[10];
    float* out = (float*)d_out;

    const int N = NN;
    const int E = in_sizes[2];

    char* ws = (char*)d_ws;
    size_t o = 0;
    auto alloc = [&](size_t b) -> char* {
        char* p = ws + o;
        o = (o + b + 255) & ~(size_t)255;
        return p;
    };
    float* h1   = (float*)alloc((size_t)N * NH * 4);   // GEMM1 out; reused for GEMM2 out
    float* h1a  = (float*)alloc((size_t)N * NH * 4);
    float* h2a  = (float*)alloc((size_t)N * NH * 4);
    unsigned short* W1T = (unsigned short*)alloc((size_t)NH * NF * 2);
    unsigned short* W2T = (unsigned short*)alloc((size_t)NH * NH * 2);
    int*   csrc = (int*)alloc((size_t)E * 4);
    float* cwv  = (float*)alloc((size_t)E * 4);
    int*   offs = (int*)alloc((size_t)(N + 1) * 4);
    int*   excl = (int*)alloc((size_t)N * 4);
    int*   bsum = (int*)alloc(512);
    float* dinv = (float*)alloc((size_t)N * 4);
    float* bnscale = (float*)alloc(NH * 4);
    float* bnshift = (float*)alloc(NH * 4);
    // contiguous zero-init region:
    char* zbase = ws + o;
    float* deg    = (float*)alloc((size_t)N * 4);
    int*   cnt    = (int*)alloc((size_t)N * 4);
    int*   cursor = (int*)alloc((size_t)N * 4);
    float* bnsum  = (float*)alloc(NH * 4);
    float* bnsq   = (float*)alloc(NH * 4);
    size_t zbytes = (size_t)((ws + o) - zbase);
    (void)hipMemsetAsync(zbase, 0, zbytes, stream);

    cvt_w<<<(NF * NH + 255) / 256, 256, 0, stream>>>(W1, W1T, NF, NF * NH);
    cvt_w<<<(NH * NH + 255) / 256, 256, 0, stream>>>(W2, W2T, NH, NH * NH);
    deg_count<<<(E + 255) / 256, 256, 0, stream>>>(ei, ew, deg, cnt, E);
    dinv_k<<<(N + 255) / 256, 256, 0, stream>>>(deg, dinv, N);
    scan_a<<<(N + 511) / 512, 512, 0, stream>>>(cnt, excl, bsum, N);
    scan_b<<<1, 128, 0, stream>>>(bsum, (N + 511) / 512);
    scan_c<<<(N + 1 + 255) / 256, 256, 0, stream>>>(excl, bsum, offs, N, E);
    scatter_k<<<(E + 255) / 256, 256, 0, stream>>>(ei, ew, offs, cursor, dinv, csrc, cwv, E);

    dim3 gg(2, (N + 127) / 128);
    gemm_f16<<<gg, 256, 0, stream>>>(x, W1T, h1, N, NF);
    agg_relu<<<(N + 3) / 4, 256, 0, stream>>>(h1, offs, csrc, cwv, dinv, b1, h1a, N);
    gemm_f16<<<gg, 256, 0, stream>>>(h1a, W2T, h1, N, NH);
    agg_relu<<<(N + 3) / 4, 256, 0, stream>>>(h1, offs, csrc, cwv, dinv, b2, h2a, N);

    bn_stats<<<256, 256, 0, stream>>>(h2a, bnsum, bnsq, N);
    bn_params<<<1, 256, 0, stream>>>(bnsum, bnsq, bng, bnb, bnscale, bnshift, N);
    bn_ln<<<(N + 3) / 4, 256, 0, stream>>>(h2a, bnscale, bnshift, lng, lnb, out, N);
}

// Round 2
// 702.333 us; speedup vs baseline: 1.1854x; 1.1854x over previous
//
#include <hip/hip_runtime.h>

// GCN pipeline on MI355X, round 2:
//   deg/dinv -> CSR(by dst) -> GEMM1(fp32 A, pipelined dbuf, f16 MFMA) -> agg+relu(f16)
//   -> GEMM2(f16 A via glds) -> agg+relu(f16) -> BN stats -> fused BN+LN -> out(fp32)
// Intermediates h1/h1a/h2/h2a stored f16; all accumulation fp32.

typedef __attribute__((ext_vector_type(4))) float f32x4;
typedef __attribute__((ext_vector_type(8))) _Float16 f16x8;
typedef __attribute__((ext_vector_type(4))) _Float16 f16x4;

#define NN 50000
#define NF 1024
#define NH 256

// ---------------- small kernels: degree / dinv -------------------------------
__global__ __launch_bounds__(256) void deg_count(const int* __restrict__ ei,
    const float* __restrict__ ew, float* __restrict__ deg, int* __restrict__ cnt, int E)
{
    int e = blockIdx.x * 256 + threadIdx.x;
    if (e >= E) return;
    int d = ei[E + e];
    atomicAdd(&deg[d], ew[e]);
    atomicAdd(&cnt[d], 1);
}

__global__ __launch_bounds__(256) void dinv_k(const float* __restrict__ deg,
    float* __restrict__ dinv, int n)
{
    int i = blockIdx.x * 256 + threadIdx.x;
    if (i < n) dinv[i] = rsqrtf(deg[i] + 1.0f);   // +1 = self-loop weight
}

// ---------------- CSR build: 3-kernel exclusive scan + scatter ---------------
__global__ __launch_bounds__(512) void scan_a(const int* __restrict__ cnt,
    int* __restrict__ excl, int* __restrict__ bsum, int n)
{
    __shared__ int sm[512];
    int t = threadIdx.x, g = blockIdx.x * 512 + t;
    int v = (g < n) ? cnt[g] : 0;
    sm[t] = v;
    __syncthreads();
    for (int d = 1; d < 512; d <<= 1) {
        int x = (t >= d) ? sm[t - d] : 0;
        __syncthreads();
        sm[t] += x;
        __syncthreads();
    }
    if (g < n) excl[g] = sm[t] - v;
    if (t == 511) bsum[blockIdx.x] = sm[511];
}

__global__ __launch_bounds__(128) void scan_b(int* __restrict__ bsum, int nb)
{
    __shared__ int sm[128];
    int t = threadIdx.x;
    int v = (t < nb) ? bsum[t] : 0;
    sm[t] = v;
    __syncthreads();
    for (int d = 1; d < 128; d <<= 1) {
        int x = (t >= d) ? sm[t - d] : 0;
        __syncthreads();
        sm[t] += x;
        __syncthreads();
    }
    if (t < nb) bsum[t] = sm[t] - v;
}

__global__ __launch_bounds__(256) void scan_c(const int* __restrict__ excl,
    const int* __restrict__ bsum, int* __restrict__ offs, int n, int E)
{
    int g = blockIdx.x * 256 + threadIdx.x;
    if (g < n) offs[g] = excl[g] + bsum[g >> 9];
    else if (g == n) offs[n] = E;
}

__global__ __launch_bounds__(256) void scatter_k(const int* __restrict__ ei,
    const float* __restrict__ ew, const int* __restrict__ offs,
    int* __restrict__ cursor, const float* __restrict__ dinv,
    int* __restrict__ csrc, float* __restrict__ cwv, int E)
{
    int e = blockIdx.x * 256 + threadIdx.x;
    if (e >= E) return;
    int s = ei[e], d = ei[E + e];
    int pos = offs[d] + atomicAdd(&cursor[d], 1);
    csrc[pos] = s;
    cwv[pos] = ew[e] * dinv[s] * dinv[d];
}

// ---------------- W -> W^T f16 conversion ------------------------------------
__global__ __launch_bounds__(256) void cvt_w(const float* __restrict__ W,
    unsigned short* __restrict__ WT, int K, int total)
{
    int idx = blockIdx.x * 256 + threadIdx.x;
    if (idx >= total) return;
    int k = idx >> 8, n = idx & 255;
    ((_Float16*)WT)[(size_t)n * K + k] = (_Float16)W[idx];
}

// ---------------- GEMM: C[M][256](f16) = A[M][K] * B[K][256], f16 MFMA -------
// 128x128 tile, 4 waves. Double-buffered LDS, single barrier/iter, prefetch:
//  - AF32: A fp32 -> VGPR prefetch (issued post-barrier, overlaps MFMA) -> cvt ->
//          ds_write into padded LDS (stride 40 f16, conflict-free 16B reads)
//  - !AF32: A f16 staged via global_load_lds (m97 structure), stride 32
//  - B^T f16 always via global_load_lds, issued one iter ahead.
template<bool AF32>
__global__ __launch_bounds__(256) void gemm_mfma(
    const void* __restrict__ Av, const unsigned short* __restrict__ BT,
    _Float16* __restrict__ C, int M, int K)
{
    constexpr int AS = AF32 ? 40 : 32;          // LDS A row stride in f16
    __shared__ _Float16 As[2][128 * AS];
    __shared__ _Float16 Bs[2][128 * 32];
    const int t = threadIdx.x;
    const int lane = t & 63, wid = t >> 6;
    const int r = lane & 15, q = lane >> 4;
    const int n0 = blockIdx.x * 128;
    const int m0 = blockIdx.y * 128;
    const int wm = (wid >> 1) * 64, wn = (wid & 1) * 64;
    const float* Af = (const float*)Av;
    const _Float16* Ah = (const _Float16*)Av;

    f32x4 acc[4][4];
#pragma unroll
    for (int i = 0; i < 4; ++i)
#pragma unroll
        for (int j = 0; j < 4; ++j) acc[i][j] = (f32x4){0.f, 0.f, 0.f, 0.f};

    const int T = K >> 5;   // K/32 iterations
    float4 a_pre[4];

    // ---- preload k=0 ----
    if constexpr (AF32) {
#pragma unroll
        for (int it = 0; it < 4; ++it) {
            int f = it * 256 + t;
            int m = f >> 3, kc = (f & 7) << 2;
            int gm = m0 + m; if (gm >= M) gm = M - 1;
            a_pre[it] = *(const float4*)(Af + (size_t)gm * K + kc);
        }
    } else {
#pragma unroll
        for (int rd = 0; rd < 2; ++rd) {
            int row = rd * 64 + (t >> 2), kc = (t & 3) << 3;
            int gm = m0 + row; if (gm >= M) gm = M - 1;
            const _Float16* g = Ah + (size_t)gm * K + kc;
            _Float16* l = &As[0][0] + rd * 2048 + wid * 512;   // wave-uniform base
            __builtin_amdgcn_global_load_lds(
                (const __attribute__((address_space(1))) unsigned int*)g,
                (__attribute__((address_space(3))) unsigned int*)l, 16, 0, 0);
        }
    }
#pragma unroll
    for (int rd = 0; rd < 2; ++rd) {
        int c = rd * 256 + t;
        int n = c >> 2, kc = (c & 3) << 3;
        const _Float16* g = (const _Float16*)BT + (size_t)(n0 + n) * K + kc;
        _Float16* l = &Bs[0][0] + rd * 2048 + wid * 512;
        __builtin_amdgcn_global_load_lds(
            (const __attribute__((address_space(1))) unsigned int*)g,
            (__attribute__((address_space(3))) unsigned int*)l, 16, 0, 0);
    }

    for (int k = 0; k < T; ++k) {
        const int cur = k & 1, nxt = cur ^ 1;
        if constexpr (AF32) {
            // cvt prefetched regs -> LDS (waits vmcnt on a_pre here)
#pragma unroll
            for (int it = 0; it < 4; ++it) {
                int f = it * 256 + t;
                int m = f >> 3, kc = (f & 7) << 2;
                f16x4 hv;
                hv.x = (_Float16)a_pre[it].x; hv.y = (_Float16)a_pre[it].y;
                hv.z = (_Float16)a_pre[it].z; hv.w = (_Float16)a_pre[it].w;
                *(f16x4*)(&As[cur][0] + m * AS + kc) = hv;
            }
        }
        __syncthreads();   // drains glds issued last iter (latency hidden by MFMA)

        if (k + 1 < T) {
            const int k1 = (k + 1) << 5;
#pragma unroll
            for (int rd = 0; rd < 2; ++rd) {
                int c = rd * 256 + t;
                int n = c >> 2, kc = (c & 3) << 3;
                const _Float16* g = (const _Float16*)BT + (size_t)(n0 + n) * K + k1 + kc;
                _Float16* l = &Bs[nxt][0] + rd * 2048 + wid * 512;
                __builtin_amdgcn_global_load_lds(
                    (const __attribute__((address_space(1))) unsigned int*)g,
                    (__attribute__((address_space(3))) unsigned int*)l, 16, 0, 0);
            }
            if constexpr (AF32) {
#pragma unroll
                for (int it = 0; it < 4; ++it) {
                    int f = it * 256 + t;
                    int m = f >> 3, kc = (f & 7) << 2;
                    int gm = m0 + m; if (gm >= M) gm = M - 1;
                    a_pre[it] = *(const float4*)(Af + (size_t)gm * K + k1 + kc);
                }
            } else {
#pragma unroll
                for (int rd = 0; rd < 2; ++rd) {
                    int row = rd * 64 + (t >> 2), kc = (t & 3) << 3;
                    int gm = m0 + row; if (gm >= M) gm = M - 1;
                    const _Float16* g = Ah + (size_t)gm * K + k1 + kc;
                    _Float16* l = &As[nxt][0] + rd * 2048 + wid * 512;
                    __builtin_amdgcn_global_load_lds(
                        (const __attribute__((address_space(1))) unsigned int*)g,
                        (__attribute__((address_space(3))) unsigned int*)l, 16, 0, 0);
                }
            }
        }

        f16x8 af[4], bfr[4];
#pragma unroll
        for (int i = 0; i < 4; ++i)
            af[i] = *(const f16x8*)(&As[cur][0] + (wm + i * 16 + r) * AS + q * 8);
#pragma unroll
        for (int j = 0; j < 4; ++j)
            bfr[j] = *(const f16x8*)(&Bs[cur][0] + (wn + j * 16 + r) * 32 + q * 8);
#pragma unroll
        for (int i = 0; i < 4; ++i)
#pragma unroll
            for (int j = 0; j < 4; ++j)
                acc[i][j] = __builtin_amdgcn_mfma_f32_16x16x32_f16(af[i], bfr[j], acc[i][j], 0, 0, 0);
    }

    // epilogue: D[row=q*4+reg][col=r] per 16x16 tile
#pragma unroll
    for (int i = 0; i < 4; ++i) {
#pragma unroll
        for (int reg = 0; reg < 4; ++reg) {
            int m = m0 + wm + i * 16 + q * 4 + reg;
            if (m < M) {
                _Float16* cp = C + (size_t)m * 256 + (n0 + wn + r);
#pragma unroll
                for (int j = 0; j < 4; ++j) cp[j * 16] = (_Float16)acc[i][j][reg];
            }
        }
    }
}

// ---------------- aggregation: out = relu(A_hat @ h + b), f16 in/out ---------
// 1 wave per node; lane holds cols [4*lane, 4*lane+4). Edge metadata loaded
// cooperatively (64 edges/coalesced load) and broadcast via shfl.
__global__ __launch_bounds__(256) void agg_relu(
    const _Float16* __restrict__ h, const int* __restrict__ roff,
    const int* __restrict__ csrc, const float* __restrict__ cwv,
    const float* __restrict__ dinv, const float* __restrict__ bias,
    _Float16* __restrict__ out, int n)
{
    const int lane = threadIdx.x & 63, wid = threadIdx.x >> 6;
    const int i = blockIdx.x * 4 + wid;
    if (i >= n) return;
    const int c = lane << 2;
    const float di = dinv[i];
    const float sw = di * di;
    const f16x4 hv = *(const f16x4*)(h + (size_t)i * 256 + c);
    float a0 = sw * (float)hv.x, a1 = sw * (float)hv.y;
    float a2 = sw * (float)hv.z, a3 = sw * (float)hv.w;
    float c0 = 0.f, c1 = 0.f, c2 = 0.f, c3 = 0.f;
    const int p0 = roff[i], pe = roff[i + 1];
    for (int base = p0; base < pe; base += 64) {
        int lim = pe - base; if (lim > 64) lim = 64;
        int sv = 0; float wv = 0.f;
        if (lane < lim) { sv = csrc[base + lane]; wv = cwv[base + lane]; }
        int j = 0;
        for (; j + 1 < lim; j += 2) {
            int s0 = __shfl(sv, j), s1 = __shfl(sv, j + 1);
            float w0 = __shfl(wv, j), w1 = __shfl(wv, j + 1);
            f16x4 v0 = *(const f16x4*)(h + (size_t)s0 * 256 + c);
            f16x4 v1 = *(const f16x4*)(h + (size_t)s1 * 256 + c);
            a0 += w0 * (float)v0.x; a1 += w0 * (float)v0.y;
            a2 += w0 * (float)v0.z; a3 += w0 * (float)v0.w;
            c0 += w1 * (float)v1.x; c1 += w1 * (float)v1.y;
            c2 += w1 * (float)v1.z; c3 += w1 * (float)v1.w;
        }
        if (j < lim) {
            int s0 = __shfl(sv, j);
            float w0 = __shfl(wv, j);
            f16x4 v0 = *(const f16x4*)(h + (size_t)s0 * 256 + c);
            a0 += w0 * (float)v0.x; a1 += w0 * (float)v0.y;
            a2 += w0 * (float)v0.z; a3 += w0 * (float)v0.w;
        }
    }
    const float4 bb = *(const float4*)(bias + c);
    f16x4 o;
    o.x = (_Float16)fmaxf(a0 + c0 + bb.x, 0.f);
    o.y = (_Float16)fmaxf(a1 + c1 + bb.y, 0.f);
    o.z = (_Float16)fmaxf(a2 + c2 + bb.z, 0.f);
    o.w = (_Float16)fmaxf(a3 + c3 + bb.w, 0.f);
    *(f16x4*)(out + (size_t)i * 256 + c) = o;
}

// ---------------- BatchNorm stats (per-column over rows), f16 in -------------
__global__ __launch_bounds__(256) void bn_stats(const _Float16* __restrict__ h,
    float* __restrict__ bnsum, float* __restrict__ bnsq, int n)
{
    const int t = threadIdx.x;
    float s = 0.f, s2 = 0.f;
    for (int r = blockIdx.x; r < n; r += gridDim.x) {
        float v = (float)h[(size_t)r * 256 + t];
        s += v; s2 += v * v;
    }
    atomicAdd(&bnsum[t], s);
    atomicAdd(&bnsq[t], s2);
}

__global__ __launch_bounds__(256) void bn_params(const float* __restrict__ bnsum,
    const float* __restrict__ bnsq, const float* __restrict__ gamma,
    const float* __restrict__ beta, float* __restrict__ scale,
    float* __restrict__ shift, int n)
{
    int t = threadIdx.x;
    float mu = bnsum[t] / (float)n;
    float var = bnsq[t] / (float)n - mu * mu;
    float sc = gamma[t] * rsqrtf(var + 1e-5f);
    scale[t] = sc;
    shift[t] = beta[t] - mu * sc;
}

// ---------------- fused BN affine + LayerNorm, f16 in / fp32 out -------------
__global__ __launch_bounds__(256) void bn_ln(const _Float16* __restrict__ h,
    const float* __restrict__ scale, const float* __restrict__ shift,
    const float* __restrict__ lng, const float* __restrict__ lnb,
    float* __restrict__ out, int n)
{
    const int lane = threadIdx.x & 63, wid = threadIdx.x >> 6;
    const int i = blockIdx.x * 4 + wid;
    if (i >= n) return;
    const int c = lane << 2;
    const f16x4 v = *(const f16x4*)(h + (size_t)i * 256 + c);
    const float4 sc = *(const float4*)(scale + c);
    const float4 sh = *(const float4*)(shift + c);
    float y0 = (float)v.x * sc.x + sh.x;
    float y1 = (float)v.y * sc.y + sh.y;
    float y2 = (float)v.z * sc.z + sh.z;
    float y3 = (float)v.w * sc.w + sh.w;
    float ps = y0 + y1 + y2 + y3;
    float ps2 = y0 * y0 + y1 * y1 + y2 * y2 + y3 * y3;
#pragma unroll
    for (int off = 32; off > 0; off >>= 1) {
        ps += __shfl_down(ps, off);
        ps2 += __shfl_down(ps2, off);
    }
    ps = __shfl(ps, 0);
    ps2 = __shfl(ps2, 0);
    const float mu = ps * (1.f / 256.f);
    const float var = ps2 * (1.f / 256.f) - mu * mu;
    const float rs = rsqrtf(var + 1e-5f);
    const float4 g = *(const float4*)(lng + c);
    const float4 bb = *(const float4*)(lnb + c);
    float4 o;
    o.x = (y0 - mu) * rs * g.x + bb.x;
    o.y = (y1 - mu) * rs * g.y + bb.y;
    o.z = (y2 - mu) * rs * g.z + bb.z;
    o.w = (y3 - mu) * rs * g.w + bb.w;
    *(float4*)(out + (size_t)i * 256 + c) = o;
}

// ---------------- launcher ---------------------------------------------------
extern "C" void kernel_launch(void* const* d_in, const int* in_sizes, int n_in,
                              void* d_out, int out_size, void* d_ws, size_t ws_size,
                              hipStream_t stream)
{
    const float* x   = (const float*)d_in[0];
    const int*   ei  = (const int*)d_in[1];
    const float* ew  = (const float*)d_in[2];
    const float* W1  = (const float*)d_in[3];
    const float* b1  = (const float*)d_in[4];
    const float* W2  = (const float*)d_in[5];
    const float* b2  = (const float*)d_in[6];
    const float* bng = (const float*)d_in[7];
    const float* bnb = (const float*)d_in[8];
    const float* lng = (const float*)d_in[9];
    const float* lnb = (const float*)d_in[10];
    float* out = (float*)d_out;

    const int N = NN;
    const int E = in_sizes[2];

    char* ws = (char*)d_ws;
    size_t o = 0;
    auto alloc = [&](size_t b) -> char* {
        char* p = ws + o;
        o = (o + b + 255) & ~(size_t)255;
        return p;
    };
    _Float16* h1  = (_Float16*)alloc((size_t)N * NH * 2);   // GEMM out (reused for h2)
    _Float16* h1a = (_Float16*)alloc((size_t)N * NH * 2);
    _Float16* h2a = (_Float16*)alloc((size_t)N * NH * 2);
    unsigned short* W1T = (unsigned short*)alloc((size_t)NH * NF * 2);
    unsigned short* W2T = (unsigned short*)alloc((size_t)NH * NH * 2);
    int*   csrc = (int*)alloc((size_t)E * 4);
    float* cwv  = (float*)alloc((size_t)E * 4);
    int*   offs = (int*)alloc((size_t)(N + 1) * 4);
    int*   excl = (int*)alloc((size_t)N * 4);
    int*   bsum = (int*)alloc(512);
    float* dinv = (float*)alloc((size_t)N * 4);
    float* bnscale = (float*)alloc(NH * 4);
    float* bnshift = (float*)alloc(NH * 4);
    char* zbase = ws + o;
    float* deg    = (float*)alloc((size_t)N * 4);
    int*   cnt    = (int*)alloc((size_t)N * 4);
    int*   cursor = (int*)alloc((size_t)N * 4);
    float* bnsum  = (float*)alloc(NH * 4);
    float* bnsq   = (float*)alloc(NH * 4);
    size_t zbytes = (size_t)((ws + o) - zbase);
    (void)hipMemsetAsync(zbase, 0, zbytes, stream);

    cvt_w<<<(NF * NH + 255) / 256, 256, 0, stream>>>(W1, W1T, NF, NF * NH);
    cvt_w<<<(NH * NH + 255) / 256, 256, 0, stream>>>(W2, W2T, NH, NH * NH);
    deg_count<<<(E + 255) / 256, 256, 0, stream>>>(ei, ew, deg, cnt, E);
    dinv_k<<<(N + 255) / 256, 256, 0, stream>>>(deg, dinv, N);
    scan_a<<<(N + 511) / 512, 512, 0, stream>>>(cnt, excl, bsum, N);
    scan_b<<<1, 128, 0, stream>>>(bsum, (N + 511) / 512);
    scan_c<<<(N + 1 + 255) / 256, 256, 0, stream>>>(excl, bsum, offs, N, E);
    scatter_k<<<(E + 255) / 256, 256, 0, stream>>>(ei, ew, offs, cursor, dinv, csrc, cwv, E);

    dim3 gg(2, (N + 127) / 128);
    gemm_mfma<true><<<gg, 256, 0, stream>>>(x, W1T, h1, N, NF);
    agg_relu<<<(N + 3) / 4, 256, 0, stream>>>(h1, offs, csrc, cwv, dinv, b1, h1a, N);
    gemm_mfma<false><<<gg, 256, 0, stream>>>(h1a, W2T, h1, N, NH);
    agg_relu<<<(N + 3) / 4, 256, 0, stream>>>(h1, offs, csrc, cwv, dinv, b2, h2a, N);

    bn_stats<<<256, 256, 0, stream>>>(h2a, bnsum, bnsq, N);
    bn_params<<<1, 256, 0, stream>>>(bnsum, bnsq, bng, bnb, bnscale, bnshift, N);
    bn_ln<<<(N + 3) / 4, 256, 0, stream>>>(h2a, bnscale, bnshift, lng, lnb, out, N);
}